// Round 13
// baseline (13363.782 us; speedup 1.0000x reference)
//
#include <hip/hip_runtime.h>

typedef _Float16 half8 __attribute__((ext_vector_type(8)));
typedef float floatx4 __attribute__((ext_vector_type(4)));

#define S_LEN 512
#define NB 64
#define NI 256
#define NR 2048
#define LEAK 0.9f

#define NBLK 128
#define TPB 1024              /* 16 waves: 4 waves/SIMD (was 2) */
#define LBLK 64
#define NBNR ((size_t)NB * NR)

// ---- workspace offsets ----
#define OFF_BAR ((size_t)0)
#define OFF_H0  ((size_t)4096)                 /* 2-parity fragment-order h exch, layer0 (=y0) */
#define OFF_H1  (OFF_H0 + 2 * NBNR * 2)        /* layer1 */
#define OFF_XE  (OFF_H1 + 2 * NBNR * 2)        /* x in fragment order, per t */

__device__ __forceinline__ half8 cvt8(const float* s) {
    float4 p = *(const float4*)s, q = *(const float4*)(s + 4);
    half8 v;
    v[0] = (_Float16)p.x; v[1] = (_Float16)p.y; v[2] = (_Float16)p.z; v[3] = (_Float16)p.w;
    v[4] = (_Float16)q.x; v[5] = (_Float16)q.y; v[6] = (_Float16)q.z; v[7] = (_Float16)q.w;
    return v;
}

// x fp32 -> fp16 in fragment order: per t, 32 units of 1KB; unit u=(bt*8+c),
// element (l*8+e) <-> (batch=bt*16+(l&15), i=c*32+(l>>4)*8+e)  (R5-proven)
__global__ void xprep_kernel(const float* __restrict__ x, _Float16* __restrict__ xe) {
    const int t = blockIdx.x;
    #pragma unroll
    for (int it = 0; it < 4; ++it) {
        const int u = it * 8 + (threadIdx.x >> 6);
        const int l = threadIdx.x & 63;
        const int b = (u >> 3) * 16 + (l & 15);
        const int i0 = (u & 7) * 32 + (l >> 4) * 8;
        half8 v = cvt8(x + ((size_t)t * NB + b) * NI + i0);
        *(half8*)(xe + (size_t)t * NB * NI + (size_t)u * 512 + (size_t)l * 8) = v;
    }
}

// two-level grid barrier with release/acquire threadfence (R5-proven, verbatim)
__device__ __forceinline__ void gbar(unsigned* bar) {
    __syncthreads();
    if (threadIdx.x == 0) {
        __threadfence();                   // release: L2 writeback
        unsigned* cnt  = bar + (blockIdx.x & 7) * 32;
        unsigned* root = bar + 256;
        unsigned* gen  = bar + 272;
        unsigned g = __hip_atomic_load(gen, __ATOMIC_RELAXED, __HIP_MEMORY_SCOPE_AGENT);
        bool last = false;
        if (__hip_atomic_fetch_add(cnt, 1u, __ATOMIC_ACQ_REL, __HIP_MEMORY_SCOPE_AGENT) == (NBLK / 8 - 1)) {
            __hip_atomic_store(cnt, 0u, __ATOMIC_RELAXED, __HIP_MEMORY_SCOPE_AGENT);
            if (__hip_atomic_fetch_add(root, 1u, __ATOMIC_ACQ_REL, __HIP_MEMORY_SCOPE_AGENT) == 7u) {
                __hip_atomic_store(root, 0u, __ATOMIC_RELAXED, __HIP_MEMORY_SCOPE_AGENT);
                __hip_atomic_store(gen, g + 1u, __ATOMIC_RELEASE, __HIP_MEMORY_SCOPE_AGENT);
                last = true;
            }
        }
        if (!last)
            while (__hip_atomic_load(gen, __ATOMIC_RELAXED, __HIP_MEMORY_SCOPE_AGENT) == g)
                __builtin_amdgcn_s_sleep(1);
        __threadfence();                   // acquire: cache invalidate
    }
    __syncthreads();
}

// One layer, persistent. 16 waves/block; wave w owns 4 recurrent k-chunks
// (w*4..w*4+3) + input chunks (L0: waves 8-15 one each; L1: w*4..w*4+3).
// h exchange in MFMA fragment order (R5): unit (bt*64+chunk)*1024B, byte lane*16.
template <int ROLE>
__device__ __forceinline__ void esn_layer_run(
    const float* __restrict__ bias_v,
    const float* __restrict__ Whh, const float* __restrict__ Win,
    const char* __restrict__ xe,
    char* __restrict__ hp,
    const char* __restrict__ h0p,
    float* __restrict__ out,
    unsigned* __restrict__ bar,
    float* __restrict__ rsc, int r0)
{
    const int tid = threadIdx.x;
    const int l = tid & 63, w = tid >> 6, l15 = l & 15, g = l >> 4;   // w: 0..15
    constexpr int KU = ROLE ? NR : NI;

    // ---- this wave's W slices (4 rec chunks + chi input chunks), 2 fg ----
    half8 wrA[4], wrB[4];
    #pragma unroll
    for (int j = 0; j < 4; ++j) {
        const float* s = Whh + (size_t)(r0 + l15) * NR + (w * 4 + j) * 32 + g * 8;
        wrA[j] = cvt8(s);
        wrB[j] = cvt8(s + (size_t)16 * NR);
    }
    const int chi = (ROLE == 1) ? 4 : ((w >= 8) ? 1 : 0);
    const int ci0 = (ROLE == 1) ? w * 4 : (w - 8);
    half8 wiA[4], wiB[4];
    #pragma unroll
    for (int j = 0; j < 4; ++j) {
        if (j < chi) {
            const float* s = Win + (size_t)(r0 + l15) * KU + (ci0 + j) * 32 + g * 8;
            wiA[j] = cvt8(s);
            wiB[j] = cvt8(s + (size_t)16 * KU);
        }
    }

    // owners: waves 0..7, tile (fg_o = w&1, bt_o = w>>1)
    const int fg_o = w & 1, bt_o = w >> 1;
    const bool owner = (w < 8);
    const int ncol = r0 + fg_o * 16 + l15;
    const int bj0 = bt_o * 16 + g * 4;
    const float bias = owner ? bias_v[ncol] : 0.f;
    const int cu = ncol >> 5, gg = (ncol >> 3) & 3, ee = ncol & 7;
    float hs[4] = {0.f, 0.f, 0.f, 0.f};
    float* hn_base = out + (size_t)S_LEN * NBNR + (size_t)ROLE * NBNR;

    for (int s = 0; s < S_LEN + 1; ++s) {
        const int t = (ROLE == 0) ? s : s - 1;
        const bool active = (ROLE == 0) ? (s < S_LEN) : (s >= 1);
        if (active) {
            const char* hu = hp + (size_t)(t & 1) * (NBNR * 2);
            const char* uu = (ROLE == 0) ? xe + (size_t)t * NB * NI * 2
                                         : h0p + (size_t)((t + 1) & 1) * (NBNR * 2);

            floatx4 acc[2][4];
            #pragma unroll
            for (int fg = 0; fg < 2; ++fg)
                #pragma unroll
                for (int bt = 0; bt < 4; ++bt)
                    acc[fg][bt] = (floatx4){0.f, 0.f, 0.f, 0.f};

            #pragma unroll
            for (int bt = 0; bt < 4; ++bt) {
                // recurrent: 4 chunk loads then 8 MFMAs
                half8 ar[4];
                #pragma unroll
                for (int j = 0; j < 4; ++j)
                    ar[j] = *(const half8*)(hu + ((size_t)(bt * 64 + w * 4 + j) << 10) + (size_t)l * 16);
                #pragma unroll
                for (int j = 0; j < 4; ++j) {
                    acc[0][bt] = __builtin_amdgcn_mfma_f32_16x16x32_f16(ar[j], wrA[j], acc[0][bt], 0, 0, 0);
                    acc[1][bt] = __builtin_amdgcn_mfma_f32_16x16x32_f16(ar[j], wrB[j], acc[1][bt], 0, 0, 0);
                }
                // input part
                half8 av[4];
                #pragma unroll
                for (int j = 0; j < 4; ++j) {
                    if (j < chi) {
                        const size_t unit = (ROLE == 1) ? (size_t)(bt * 64 + ci0 + j)
                                                        : (size_t)(bt * 8 + ci0);
                        av[j] = *(const half8*)(uu + (unit << 10) + (size_t)l * 16);
                    }
                }
                #pragma unroll
                for (int j = 0; j < 4; ++j) {
                    if (j < chi) {
                        acc[0][bt] = __builtin_amdgcn_mfma_f32_16x16x32_f16(av[j], wiA[j], acc[0][bt], 0, 0, 0);
                        acc[1][bt] = __builtin_amdgcn_mfma_f32_16x16x32_f16(av[j], wiB[j], acc[1][bt], 0, 0, 0);
                    }
                }
            }

            // cross-wave K reduction: 16 waves x 8 tiles x 1KB (contiguous, conflict-free)
            #pragma unroll
            for (int fg = 0; fg < 2; ++fg)
                #pragma unroll
                for (int bt = 0; bt < 4; ++bt)
                    *(floatx4*)(rsc + (size_t)((w * 8 + fg * 4 + bt) * 64 + l) * 4) = acc[fg][bt];
            __syncthreads();

            if (owner) {
                floatx4 r = {0.f, 0.f, 0.f, 0.f};
                #pragma unroll
                for (int v = 0; v < 16; ++v)
                    r += *(const floatx4*)(rsc + (size_t)((v * 8 + fg_o * 4 + bt_o) * 64 + l) * 4);

                char* hw = hp + (size_t)((t + 1) & 1) * (NBNR * 2);
                #pragma unroll
                for (int j = 0; j < 4; ++j) {
                    float hn = (1.0f - LEAK) * hs[j] + LEAK * tanhf(r[j] + bias);
                    hs[j] = hn;
                    const int bj = bj0 + j;
                    // fragment-order publish (plain store; barrier's threadfence flushes)
                    size_t byte = (size_t)((bj >> 4) * 64 + cu) * 1024
                                + (size_t)((gg * 16 + (bj & 15)) * 8 + ee) * 2;
                    *(_Float16*)(hw + byte) = (_Float16)hn;
                    if (ROLE == 1)
                        __builtin_nontemporal_store(hn, out + (size_t)t * NBNR + (size_t)bj * NR + ncol);
                    if (t == S_LEN - 1)
                        __builtin_nontemporal_store(hn, hn_base + (size_t)bj * NR + ncol);
                }
            }
        }
        if (s < S_LEN) gbar(bar);
    }
}

// blocks 0..63: layer 0 (step s); blocks 64..127: layer 1 (step s-1)
__global__ void __launch_bounds__(TPB, 1) esn_kernel(
    const float* __restrict__ b0v, const float* __restrict__ b1v,
    const float* __restrict__ Whh0, const float* __restrict__ Win0,
    const float* __restrict__ Whh1, const float* __restrict__ Win1,
    const char* __restrict__ xe,
    char* __restrict__ h0p, char* __restrict__ h1p,
    unsigned* __restrict__ bar, float* __restrict__ out)
{
    __shared__ __align__(16) float rsc[128 * 64 * 4];   // 128 KiB reduction scratch
    const int bid = blockIdx.x;
    if (bid < LBLK)
        esn_layer_run<0>(b0v, Whh0, Win0, xe, h0p, nullptr, out, bar, rsc, bid * 32);
    else
        esn_layer_run<1>(b1v, Whh1, Win1, nullptr, h1p, h0p, out, bar, rsc, (bid - LBLK) * 32);
}

extern "C" void kernel_launch(void* const* d_in, const int* in_sizes, int n_in,
                              void* d_out, int out_size, void* d_ws, size_t ws_size,
                              hipStream_t stream) {
    const float* x    = (const float*)d_in[0];
    const float* Win0 = (const float*)d_in[1];
    const float* Whh0 = (const float*)d_in[2];
    const float* b0   = (const float*)d_in[3];
    const float* Win1 = (const float*)d_in[4];
    const float* Whh1 = (const float*)d_in[5];
    const float* b1   = (const float*)d_in[6];

    char* ws = (char*)d_ws;
    char* xe  = ws + OFF_XE;
    char* h0p = ws + OFF_H0;
    char* h1p = ws + OFF_H1;
    unsigned* bar = (unsigned*)(ws + OFF_BAR);
    float* out = (float*)d_out;

    // zero barrier + both fragment-order h exchanges (initial state h=0)
    (void)hipMemsetAsync(ws, 0, OFF_XE, stream);

    xprep_kernel<<<dim3(S_LEN), dim3(512), 0, stream>>>(x, (_Float16*)xe);

    void* args[] = { (void*)&b0, (void*)&b1, (void*)&Whh0, (void*)&Win0,
                     (void*)&Whh1, (void*)&Win1, (void*)&xe, (void*)&h0p,
                     (void*)&h1p, (void*)&bar, (void*)&out };
    hipError_t e = hipLaunchCooperativeKernel((void*)esn_kernel, dim3(NBLK), dim3(TPB),
                                              args, 0, stream);
    if (e != hipSuccess) {
        esn_kernel<<<dim3(NBLK), dim3(TPB), 0, stream>>>(
            b0, b1, Whh0, Win0, Whh1, Win1, xe, h0p, h1p, bar, out);
    }
}